// Round 11
// baseline (3433.960 us; speedup 1.0000x reference)
//
#include <hip/hip_runtime.h>
#include <math.h>

#define NDATA   20000
#define DFEAT   1024
#define TWO_M   64
#define MM      32
#define ETA_F   1e-4f
#define THRES_F 1e-12f
#define NSWEEP  8
#define NBLK    128
#define NTHR    1024
#define NW      (NBLK*(NTHR/64))

// ---- ws layout (bytes) ----
#define O_BAR   0                  // int: barrier arrive counter (memset 0)
#define O_GEN   128                // int: barrier generation      (memset 0)
#define O_CTL   256                // int[16]: [0]=C_RCA
#define O_MIN   512                // int[NBLK] per-block winner mins
#define O_TT    1536               // int[64]   trigger time of column j
#define O_BT    2048               // float[64*1024] columns of B (row j = col j)
#define O_BASE  (O_BT + 262144)    // float[20000] segment-start scalar
#define O_SCV   (O_BASE + 80000)   // float[20000] running scalar (alive rows)
#define O_FLAG  (O_SCV + 80000)    // int[20000]   1 = still-possible trigger
#define C_RCA   0

// jacobi LDS mapping inside SH[32832]
#define TG(r,c)     SH[(r)*257 + (c)]
#define SG(cb,idx)  SH[16448 + (cb)*4096 + (idx)]
#define SU(cb,idx)  SH[24640 + (cb)*4096 + (idx)]

// interleaved lane slicing: 16B/lane stride, coalesced + LDS-conflict-free
#define LD_SLICE(P,v0,v1,v2,v3) do { v0=(P)[lane]; v1=(P)[lane+64]; v2=(P)[lane+128]; v3=(P)[lane+192]; } while(0)

__device__ __forceinline__ float wave_sum(float v) {
    v += __shfl_xor(v, 1);  v += __shfl_xor(v, 2);  v += __shfl_xor(v, 4);
    v += __shfl_xor(v, 8);  v += __shfl_xor(v, 16); v += __shfl_xor(v, 32);
    return v;
}
__device__ __forceinline__ int wave_min_i(int v) {
    v = min(v, __shfl_xor(v, 1));  v = min(v, __shfl_xor(v, 2));
    v = min(v, __shfl_xor(v, 4));  v = min(v, __shfl_xor(v, 8));
    v = min(v, __shfl_xor(v, 16)); v = min(v, __shfl_xor(v, 32));
    return v;
}
__device__ __forceinline__ void pair_from(int p, int &a, int &b) {
    int a_ = 0, rem = p;
    while (rem >= 64 - a_) { rem -= 64 - a_; ++a_; }
    a = a_; b = a_ + rem;
}
__device__ __forceinline__ float dot16(float4 x0, float4 x1, float4 x2, float4 x3,
                                       float4 y0, float4 y1, float4 y2, float4 y3) {
    float d = x0.x*y0.x + x0.y*y0.y + x0.z*y0.z + x0.w*y0.w;
    d += x1.x*y1.x + x1.y*y1.y + x1.z*y1.z + x1.w*y1.w;
    d += x2.x*y2.x + x2.y*y2.y + x2.z*y2.z + x2.w*y2.w;
    d += x3.x*y3.x + x3.y*y3.y + x3.z*y3.z + x3.w*y3.w;
    return d;
}

// ---- custom grid barrier: sense-reversing via generation counter, agent scope ----
// (validated under heavy cross-block dataflow in round 9; one atomic per block)
__device__ __forceinline__ void gbar(int* __restrict__ bar, int* __restrict__ gen) {
    __threadfence();                                   // publish this thread's writes
    __syncthreads();
    if (threadIdx.x == 0) {
        int g = __hip_atomic_load(gen, __ATOMIC_RELAXED, __HIP_MEMORY_SCOPE_AGENT);
        int a = __hip_atomic_fetch_add(bar, 1, __ATOMIC_ACQ_REL, __HIP_MEMORY_SCOPE_AGENT);
        if (a == NBLK - 1) {
            __hip_atomic_store(bar, 0, __ATOMIC_RELAXED, __HIP_MEMORY_SCOPE_AGENT);
            __hip_atomic_store(gen, g + 1, __ATOMIC_RELEASE, __HIP_MEMORY_SCOPE_AGENT);
        } else {
            while (__hip_atomic_load(gen, __ATOMIC_ACQUIRE, __HIP_MEMORY_SCOPE_AGENT) == g)
                __builtin_amdgcn_s_sleep(1);
        }
    }
    __syncthreads();
    __builtin_amdgcn_fence(__ATOMIC_ACQUIRE, "agent"); // see other blocks' writes
}

// min over minArr[0..NBLK) (NBLK=128 -> int2 per lane), broadcast via s_win
__device__ __forceinline__ int min_reduce_bcast(const int* __restrict__ minArr,
                                                int wv, int lane, int* s_win) {
    if (wv == 0) {
        int2 v = ((const int2*)minArr)[lane];
        int m = min(v.x, v.y);
        m = wave_min_i(m);
        if (lane == 0) *s_win = m;
    }
    __syncthreads();
    return *s_win;
}

// out[t] = base[t] + sum_{j in [jlo,jhi], ttime[j] < t} (Bt_j . alpha_t)^2
// Columns staged in LDS (halves of <=32 = 128 KB), single streaming pass over A per half.
__device__ void finalize_segment(const float* __restrict__ A, const float* __restrict__ base,
                                 const float* __restrict__ Bt, const int* __restrict__ ttime,
                                 float* __restrict__ out,
                                 int lo, int hi, int jlo, int jhi,
                                 float* SH, int* s_tt, int tid, int wv, int lane, int gw)
{
    int ncols = jhi - jlo + 1;
    if (ncols <= 0) {
        for (int t = lo + gw; t <= hi; t += NW)
            if (lane == 0) out[t] = base[t];
        return;
    }
    for (int h0 = jlo; h0 <= jhi; h0 += 32) {
        int nh = min(32, jhi - h0 + 1);
        __syncthreads();
        float4* S4w = (float4*)SH;
        for (int cc = wv; cc < nh; cc += 16) {
            const float4* Bj = (const float4*)(Bt + (size_t)(h0 + cc) * DFEAT);
            for (int q = 0; q < 4; ++q) S4w[cc * 256 + lane + 64 * q] = Bj[lane + 64 * q];
        }
        if (tid < nh) s_tt[tid] = ttime[h0 + tid];
        __syncthreads();
        const float4* S4 = (const float4*)SH;
        for (int t = lo + gw; t <= hi; t += NW) {
            const float4* At = (const float4*)(A + (size_t)t * DFEAT);
            float4 a0, a1, a2, a3; LD_SLICE(At, a0, a1, a2, a3);
            float o = (h0 == jlo) ? base[t] : out[t];
            for (int s = 0; s < nh; ++s) {
                if (s_tt[s] >= t) break;              // ttimes ascending within segment
                float d = dot16(a0, a1, a2, a3,
                                S4[s*256+lane], S4[s*256+lane+64],
                                S4[s*256+lane+128], S4[s*256+lane+192]);
                d = wave_sum(d);
                o += d * d;
            }
            if (lane == 0) out[t] = o;
        }
    }
}

// block-0 FD shrink: Gram -> tournament Jacobi -> sort -> remix Bt
__device__ void jacobi_shrink(float* __restrict__ Bt, int* __restrict__ ctl, float* SH,
                              float* s_rotA, float* s_rotB, int* s_prt,
                              float* s_S, float* s_Ss, int* s_perm, int* s_misc, int tid)
{
    float acc0 = 0.f, acc1 = 0.f, acc2 = 0.f;
    int a0i, b0i, a1i, b1i, a2i, b2i;
    pair_from(tid, a0i, b0i);
    pair_from(tid + 1024, a1i, b1i);
    pair_from((tid < 32) ? (tid + 2048) : 0, a2i, b2i);
    for (int c = 0; c < 4; ++c) {
        __syncthreads();
        for (int q = tid; q < 64 * 64; q += NTHR) {
            int jj = q >> 6, d4 = q & 63;
            float4 v = ((const float4*)(Bt + (size_t)jj * DFEAT + c * 256))[d4];
            TG(jj, d4*4+0) = v.x; TG(jj, d4*4+1) = v.y;
            TG(jj, d4*4+2) = v.z; TG(jj, d4*4+3) = v.w;
        }
        __syncthreads();
        for (int dd = 0; dd < 256; ++dd) {
            acc0 += TG(a0i, dd) * TG(b0i, dd);
            acc1 += TG(a1i, dd) * TG(b1i, dd);
            acc2 += TG(a2i, dd) * TG(b2i, dd);
        }
    }
    SG(0, a0i*64+b0i) = acc0; SG(0, b0i*64+a0i) = acc0;
    SG(0, a1i*64+b1i) = acc1; SG(0, b1i*64+a1i) = acc1;
    if (tid < 32) { SG(0, a2i*64+b2i) = acc2; SG(0, b2i*64+a2i) = acc2; }
    for (int e4 = 0; e4 < 4; ++e4) {
        int e = tid + e4 * 1024;
        SU(0, e) = ((e >> 6) == (e & 63)) ? 1.f : 0.f;
    }
    __syncthreads();

    int cur = 0;
    for (int sw = 0; sw < NSWEEP; ++sw) {
        for (int r = 0; r < 63; ++r) {
            if (tid < 32) {
                int p_, q_;
                if (tid == 0) { p_ = 63; q_ = r; }
                else { p_ = (r + tid) % 63; q_ = (r + 63 - tid) % 63; }
                float gpp = SG(cur, p_*64+p_);
                float gqq = SG(cur, q_*64+q_);
                float gpq = SG(cur, p_*64+q_);
                float cc = 1.f, sn = 0.f;
                if (fabsf(gpq) > 1e-20f) {
                    float tau = (gqq - gpp) / (2.f * gpq);
                    float tt  = (tau >= 0.f ? 1.f : -1.f) / (fabsf(tau) + sqrtf(1.f + tau * tau));
                    cc = 1.f / sqrtf(1.f + tt * tt);
                    sn = tt * cc;
                }
                s_rotA[p_] = cc; s_rotB[p_] = -sn; s_prt[p_] = q_;
                s_rotA[q_] = cc; s_rotB[q_] = sn;  s_prt[q_] = p_;
            }
            __syncthreads();
            float ng[4], nu[4];
            for (int e4 = 0; e4 < 4; ++e4) {
                int e = tid + e4 * 1024;
                int row = e >> 6, col = e & 63;
                int pr = s_prt[row], pc = s_prt[col];
                float ar = s_rotA[row], br = s_rotB[row];
                float ac = s_rotA[col], bc = s_rotB[col];
                ng[e4] = ar*ac*SG(cur, row*64+col) + br*ac*SG(cur, pr*64+col)
                       + ar*bc*SG(cur, row*64+pc)  + br*bc*SG(cur, pr*64+pc);
                nu[e4] = ac*SU(cur, row*64+col) + bc*SU(cur, row*64+pc);
            }
            for (int e4 = 0; e4 < 4; ++e4) {
                int e = tid + e4 * 1024;
                SG(cur ^ 1, e) = ng[e4];
                SU(cur ^ 1, e) = nu[e4];
            }
            __syncthreads();
            cur ^= 1;
        }
    }

    if (tid < 64) {
        float lam = SG(cur, tid*64+tid);
        if (lam <= THRES_F) lam = 0.f;
        s_S[tid] = lam;
    }
    __syncthreads();
    if (tid < 64) {
        float my = s_S[tid];
        int rank = 0;
        for (int i = 0; i < 64; ++i) {
            float o = s_S[i];
            rank += ((o > my) || (o == my && i < tid)) ? 1 : 0;
        }
        s_perm[rank] = tid;
        s_Ss[rank]   = my;
    }
    __syncthreads();
    if (tid == 0) {
        int nz = 0;
        for (int i = 0; i < 64; ++i) nz += (s_Ss[i] > 0.f) ? 1 : 0;
        s_misc[0] = nz;
        s_misc[1] = (nz >= MM) ? 1 : 0;
    }
    __syncthreads();
    const int nnz = s_misc[0];
    const int ge  = s_misc[1];
    const float S32 = s_Ss[MM];

    for (int e4 = 0; e4 < 4; ++e4) {
        int e = tid + e4 * 1024;
        int kk = e >> 6, jn = e & 63;
        float Sj = s_Ss[jn];
        float f;
        if (ge) f = (jn < MM - 1 && Sj > 0.f) ? sqrtf(fmaxf(Sj - S32, 0.f) / Sj) : 0.f;
        else    f = (jn < nnz) ? 1.f : 0.f;
        SG(0, kk*64+jn) = SU(cur, kk*64 + s_perm[jn]) * f;
    }
    __syncthreads();

    for (int c = 0; c < 4; ++c) {
        __syncthreads();
        for (int q = tid; q < 64 * 64; q += NTHR) {
            int jj = q >> 6, d4 = q & 63;
            float4 v = ((const float4*)(Bt + (size_t)jj * DFEAT + c * 256))[d4];
            TG(jj, d4*4+0) = v.x; TG(jj, d4*4+1) = v.y;
            TG(jj, d4*4+2) = v.z; TG(jj, d4*4+3) = v.w;
        }
        __syncthreads();
        for (int q = tid; q < 64 * 256; q += NTHR) {
            int dd = q & 255, jn = q >> 8;
            float sum = 0.f;
            for (int kk = 0; kk < 64; ++kk)
                sum += TG(kk, dd) * SG(0, kk*64+jn);
            Bt[(size_t)jn * DFEAT + c * 256 + dd] = sum;
        }
    }
    __syncthreads();
    if (tid == 0) ctl[C_RCA] = ge ? (MM - 1) : nnz;
}

// post-shrink: rebuild scv/base/flag for t > ts with NEW Bt (LDS-staged halves) + min-scan
__device__ void recompute_rows(const float* __restrict__ A, const float* __restrict__ Y,
                               const float* __restrict__ Bt,
                               float* __restrict__ scv, float* __restrict__ base,
                               int* __restrict__ flag, int ts,
                               float* SH, int* s_min, int tid, int wv, int lane, int gw)
{
    int nrows = NDATA - 1 - ts;
    int npair = (nrows + 1) >> 1;
    for (int h = 0; h < 2; ++h) {
        __syncthreads();
        {
            const float4* B4 = (const float4*)Bt;
            float4* S4w = (float4*)SH;
            for (int q = 0; q < 4; ++q) {
                S4w[wv * 256 + lane + 64*q]      = B4[(size_t)(h*32 + wv) * 256 + lane + 64*q];
                S4w[(wv+16) * 256 + lane + 64*q] = B4[(size_t)(h*32 + wv + 16) * 256 + lane + 64*q];
            }
        }
        __syncthreads();
        const float4* S4 = (const float4*)SH;
        for (int p = gw; p < npair; p += NW) {
            int tA = ts + 1 + 2*p;
            int tB = tA + 1;
            bool hasB = tB < NDATA;
            const float4* Aa = (const float4*)(A + (size_t)tA * DFEAT);
            float4 x0, x1, x2, x3; LD_SLICE(Aa, x0, x1, x2, x3);
            float4 y0 = make_float4(0,0,0,0), y1 = y0, y2 = y0, y3 = y0;
            if (hasB) {
                const float4* Ab = (const float4*)(A + (size_t)tB * DFEAT);
                LD_SLICE(Ab, y0, y1, y2, y3);
            }
            float s1 = 0.f, s2 = 0.f;
            for (int j = 0; j < 32; ++j) {
                float4 b0 = S4[j*256+lane],     b1 = S4[j*256+lane+64],
                       b2 = S4[j*256+lane+128], b3 = S4[j*256+lane+192];
                float d1 = dot16(x0,x1,x2,x3,b0,b1,b2,b3);
                d1 = wave_sum(d1);
                s1 += d1 * d1;
                float d2 = dot16(y0,y1,y2,y3,b0,b1,b2,b3);
                d2 = wave_sum(d2);
                s2 += d2 * d2;
            }
            if (lane == 0) {
                if (h == 0) {
                    scv[tA] = s1;
                    if (hasB) scv[tB] = s2;
                } else {
                    float f1 = scv[tA] + s1;
                    scv[tA] = f1; base[tA] = f1;
                    int a1v = (f1 <= Y[tA]) ? 1 : 0;
                    flag[tA] = a1v;
                    if (a1v) atomicMin(s_min, tA);
                    if (hasB) {
                        float f2 = scv[tB] + s2;
                        scv[tB] = f2; base[tB] = f2;
                        int a2v = (f2 <= Y[tB]) ? 1 : 0;
                        flag[tB] = a2v;
                        if (a2v) atomicMin(s_min, tB);
                    }
                }
            }
        }
        __syncthreads();
    }
}

__global__ __launch_bounds__(NTHR, 4)
void sftrl_v6(const float* __restrict__ A, const float* __restrict__ Y,
              float* __restrict__ out, char* __restrict__ ws)
{
    const int tid = threadIdx.x, lane = tid & 63, wv = tid >> 6, bid = blockIdx.x;
    const int gw = bid * (NTHR / 64) + wv;

    int*   bar    = (int*)(ws + O_BAR);
    int*   gen    = (int*)(ws + O_GEN);
    int*   ctl    = (int*)(ws + O_CTL);
    int*   minArr = (int*)(ws + O_MIN);
    int*   ttime  = (int*)(ws + O_TT);
    float* Bt     = (float*)(ws + O_BT);
    float* base   = (float*)(ws + O_BASE);
    float* scv    = (float*)(ws + O_SCV);
    int*   flag   = (int*)(ws + O_FLAG);

    __shared__ __attribute__((aligned(16))) float SH[32832];
    __shared__ float s_rotA[64], s_rotB[64];
    __shared__ int   s_prt[64];
    __shared__ float s_S[64], s_Ss[64];
    __shared__ int   s_perm[64], s_misc[2];
    __shared__ int   s_tt[32];
    __shared__ int   s_min, s_win;

    // ---------------- bootstrap: init + initial per-block min ----------------
    int tmin = NDATA;
    for (int t = bid * NTHR + tid; t < NDATA; t += NBLK * NTHR) {
        base[t] = 0.f; scv[t] = 0.f;
        int f = (0.f <= Y[t]) ? 1 : 0;         // scalar starts at 0
        flag[t] = f;
        if (f) tmin = min(tmin, t);
    }
    for (int i = bid * NTHR + tid; i < TWO_M * DFEAT; i += NBLK * NTHR) Bt[i] = 0.f;
    tmin = wave_min_i(tmin);
    if (tid == 0) s_min = NDATA;
    __syncthreads();
    if (lane == 0) atomicMin(&s_min, tmin);
    __syncthreads();
    if (tid == 0) minArr[bid] = s_min;
    gbar(bar, gen);
    int ts = min_reduce_bcast(minArr, wv, lane, &s_win);

    int rc = 0, fin_hi = -1, seg_lo = 1;

    // ---------------- main loop: ONE cheap barrier per trigger ----------------
    for (;;) {
        if (ts >= NDATA) {
            finalize_segment(A, base, Bt, ttime, out, fin_hi + 1, NDATA - 1,
                             seg_lo, rc, SH, s_tt, tid, wv, lane, gw);
            return;
        }

        // accept trigger ts (all blocks compute identical kap from global state)
        float sc  = scv[ts];
        float b   = Y[ts];
        float kap = sqrtf(2.f * ETA_F * (b - sc));
        rc += 1;
        if (bid == 0) {                                   // append column rc
            Bt[(size_t)rc * DFEAT + tid] = kap * A[(size_t)ts * DFEAT + tid];
            if (tid == 0) ttime[rc] = ts;
        }

        if (rc == TWO_M - 1) {
            // ============ SHRINK (statistically unreachable; kept correct) ============
            int tso = ts;
            finalize_segment(A, base, Bt, ttime, out, fin_hi + 1, tso,
                             seg_lo, rc - 1, SH, s_tt, tid, wv, lane, gw);
            gbar(bar, gen);                               // reads done before Bt rewrite
            if (bid == 0)
                jacobi_shrink(Bt, ctl, SH, s_rotA, s_rotB, s_prt, s_S, s_Ss,
                              s_perm, s_misc, tid);
            gbar(bar, gen);                               // B_new + C_RCA visible
            int rcn = ctl[C_RCA];
            if (tid == 0) s_min = NDATA;
            __syncthreads();
            recompute_rows(A, Y, Bt, scv, base, flag, tso, SH, &s_min,
                           tid, wv, lane, gw);
            __syncthreads();
            if (tid == 0) minArr[bid] = s_min;
            gbar(bar, gen);
            ts = min_reduce_bcast(minArr, wv, lane, &s_win);
            rc = rcn; fin_hi = tso; seg_lo = rcn + 1;
            continue;
        }

        // ---- fold round: rank-1 correct alive candidates, kill, find next winner ----
        if (tid == 0) s_min = NDATA;
        __syncthreads();
        const float4* Ast = (const float4*)(A + (size_t)ts * DFEAT);
        float4 as0, as1, as2, as3; LD_SLICE(Ast, as0, as1, as2, as3);
        int wmin = NDATA;
        for (int t = ts + 1 + gw; t < NDATA; t += NW) {
            if (!flag[t]) continue;                       // wave-uniform branch
            const float4* At = (const float4*)(A + (size_t)t * DFEAT);
            float4 a0, a1, a2, a3; LD_SLICE(At, a0, a1, a2, a3);
            float d = dot16(as0, as1, as2, as3, a0, a1, a2, a3);
            d = wave_sum(d);
            float v  = kap * d;
            float sc2 = scv[t] + v * v;
            if (sc2 <= Y[t]) {                            // still a candidate
                if (lane == 0) scv[t] = sc2;
                wmin = min(wmin, t);
            } else {                                      // monotone: dead forever
                if (lane == 0) flag[t] = 0;
            }
        }
        if (lane == 0) atomicMin(&s_min, wmin);
        __syncthreads();
        if (tid == 0) minArr[bid] = s_min;
        gbar(bar, gen);                                   // ---- the ONE barrier ----
        ts = min_reduce_bcast(minArr, wv, lane, &s_win);
    }
}

extern "C" void kernel_launch(void* const* d_in, const int* in_sizes, int n_in,
                              void* d_out, int out_size, void* d_ws, size_t ws_size,
                              hipStream_t stream) {
    (void)in_sizes; (void)n_in; (void)ws_size; (void)out_size;
    const float* A = (const float*)d_in[0];
    const float* Y = (const float*)d_in[1];
    float* out = (float*)d_out;
    char* ws = (char*)d_ws;

    // zero barrier counter + generation (+ ctl line)
    hipMemsetAsync(ws, 0, 512, stream);

    void* kargs[] = { (void*)&A, (void*)&Y, (void*)&out, (void*)&ws };
    hipLaunchCooperativeKernel((void*)sftrl_v6, dim3(NBLK), dim3(NTHR),
                               kargs, 0, stream);
}